// Round 9
// baseline (145.238 us; speedup 1.0000x reference)
//
#include <hip/hip_runtime.h>
#include <hip/hip_bf16.h>
#include <math.h>

// Problem constants (reference: B=64, N=512, K=32, D=64)
#define BB 64
#define NN 512
#define KK 32
#define DD 64
#define BN (BB*NN)          // 32768
#define EPSC 1e-5f
#define NEG_SLOPE 0.2f
#define NEG_INF_A (-1e9f)

typedef unsigned long long ull;

// Lessons carried: (R1) f32 inputs, not bf16. (R5) per-lane row loads from
// global are uncoalesced -> stage via LDS. (R6) lane*16+q LDS reads are
// 16-way bank-conflicted -> XOR swizzle slot = q ^ (row&15). (R7) never put
// __shfl under divergent control flow.

// ---------------------------------------------------------------------------
// KTOP (fused kA+kB): one block per row i. Computes the full 512-col cosine
// row in two 256-col chunks (64 KB LDS staging, swizzled per-lane fragments),
// writes order-preserving keys into LDS, then ranks in-block. Keys never
// touch global. ssA recomputed per-thread (16 extra FMA) -> zero cross-lane
// reduces. Block 0 additionally emits ei/ej tables + folded BN constants.
// ---------------------------------------------------------------------------
__global__ void kTop(const float* __restrict__ emb,
                     const float* __restrict__ att_em_i,
                     const float* __restrict__ att_em_j,
                     const float* __restrict__ gnn_bias,
                     const float* __restrict__ g1, const float* __restrict__ b1,
                     const float* __restrict__ m1, const float* __restrict__ v1,
                     const float* __restrict__ go, const float* __restrict__ bo,
                     const float* __restrict__ mo, const float* __restrict__ vo,
                     int* __restrict__ topk,
                     float* __restrict__ ei, float* __restrict__ ej,
                     float* __restrict__ epi) {
    __shared__ float4 As[16];        // row i (256 B)
    __shared__ float4 Bs[4096];      // 256 emb rows, XOR-swizzled (64 KiB)
    __shared__ ull keys[NN];         // 4 KiB
    const int i = blockIdx.x;
    const int t = threadIdx.x;       // 256 threads
    const float4* emb4 = (const float4*)emb;

    if (t < 16) As[t] = emb4[i*16 + t];

    for (int half = 0; half < 2; ++half) {
        const int c0 = half * 256;
        #pragma unroll
        for (int p = 0; p < 16; ++p) {           // coalesced swizzled stage
            const int idx = t + 256*p;           // 0..4095
            const int r = idx >> 4, q = idx & 15;
            Bs[(r<<4) | (q ^ (r & 15))] = emb4[c0*16 + idx];
        }
        __syncthreads();                         // Bs (and As on half 0) ready

        float dot = 0.f, ssW = 0.f, ssA = 0.f;
        #pragma unroll
        for (int q = 0; q < 16; ++q) {
            const float4 w = Bs[(t<<4) | (q ^ (t & 15))];  // 2-way max (free)
            const float4 a = As[q];                        // broadcast
            dot += a.x*w.x + a.y*w.y + a.z*w.z + a.w*w.w;
            ssW += w.x*w.x + w.y*w.y + w.z*w.z + w.w*w.w;
            ssA += a.x*a.x + a.y*a.y + a.z*a.z + a.w*a.w;
        }
        const float c = dot * rsqrtf(ssA) * rsqrtf(ssW);
        const int col = c0 + t;
        unsigned int u = __float_as_uint(c);
        u = (u & 0x80000000u) ? ~u : (u | 0x80000000u);    // order-preserving
        keys[col] = ((ull)u << 16) | (ull)(NN - 1 - col);
        __syncthreads();                         // keys written; Bs reusable
    }

    // rank selection: keys unique (index in low bits); rank = #{key > mine};
    // write at position rank -> exact lax.top_k order (value desc, idx asc).
    for (int jj = t; jj < NN; jj += 256) {
        const ull mykey = keys[jj];
        int rank = 0;
        #pragma unroll 16
        for (int kk = 0; kk < NN; ++kk) rank += (keys[kk] > mykey) ? 1 : 0;
        if (rank < KK) topk[i*KK + rank] = jj;
    }

    if (i == 0) {                    // ei/ej tables + folded BN constants
        const float4* ami = (const float4*)att_em_i;
        const float4* amj = (const float4*)att_em_j;
        for (int cc = t; cc < NN; cc += 256) {
            float e1 = 0.f, e2 = 0.f;
            #pragma unroll
            for (int q = 0; q < 16; ++q) {
                const float4 e  = emb4[cc*16 + q];
                const float4 a1 = ami[q];
                const float4 a2 = amj[q];
                e1 += e.x*a1.x + e.y*a1.y + e.z*a1.z + e.w*a1.w;
                e2 += e.x*a2.x + e.y*a2.y + e.z*a2.z + e.w*a2.w;
            }
            ei[cc] = e1; ej[cc] = e2;
        }
        if (t < DD) {
            const int d = t;
            float s1 = g1[d] / sqrtf(v1[d] + EPSC);
            float B1 = (gnn_bias[d] - m1[d]) * s1 + b1[d];
            float so = go[d] / sqrtf(vo[d] + EPSC);
            float Bo = bo[d] - mo[d] * so;
            epi[d] = s1; epi[DD + d] = B1; epi[2*DD + d] = so; epi[3*DD + d] = Bo;
        }
    }
}

// ---------------------------------------------------------------------------
// K2: xl = x @ lin_W^T + si/sj. W staged to LDS with XOR swizzle; per-lane
// fragment reads conflict-light. 2048 blocks x 16 rows. (unchanged from R8)
// ---------------------------------------------------------------------------
__global__ void k2_lin(const float* __restrict__ data,
                       const float* __restrict__ linW,
                       const float* __restrict__ att_i, const float* __restrict__ att_j,
                       const float* __restrict__ ei, const float* __restrict__ ej,
                       float* __restrict__ xl, float* __restrict__ si,
                       float* __restrict__ sj) {
    __shared__ float4 Ws[1024];         // full W, 16 KiB, XOR-swizzled
    __shared__ float4 xs[256];          // 16 rows x 16 float4 = 4 KiB
    const int t = threadIdx.x;
    const int lane = t & 63;
    const int wave = t >> 6;
    const float4* W4 = (const float4*)linW;

    #pragma unroll
    for (int p = 0; p < 4; ++p) {       // swizzled full-W stage (coalesced)
        const int idx = t + 256*p;
        const int r = idx >> 4, q = idx & 15;
        Ws[(r<<4) | (q ^ (r & 15))] = W4[idx];
    }
    xs[t] = ((const float4*)data)[blockIdx.x*256 + t];
    __syncthreads();

    float4 Wr[16];                      // W[lane][0..63], swizzled read
    #pragma unroll
    for (int q = 0; q < 16; ++q) Wr[q] = Ws[(lane<<4) | (q ^ (lane & 15))];

    const int r0 = wave * 4;            // 4 rows per wave
    float acc0 = 0.f, acc1 = 0.f, acc2 = 0.f, acc3 = 0.f;
    #pragma unroll
    for (int q = 0; q < 16; ++q) {
        const float4 w = Wr[q];
        const float4 x0 = xs[(r0+0)*16 + q];   // wave-uniform broadcasts
        const float4 x1 = xs[(r0+1)*16 + q];
        const float4 x2 = xs[(r0+2)*16 + q];
        const float4 x3 = xs[(r0+3)*16 + q];
        acc0 += x0.x*w.x + x0.y*w.y + x0.z*w.z + x0.w*w.w;
        acc1 += x1.x*w.x + x1.y*w.y + x1.z*w.z + x1.w*w.w;
        acc2 += x2.x*w.x + x2.y*w.y + x2.z*w.z + x2.w*w.w;
        acc3 += x3.x*w.x + x3.y*w.y + x3.z*w.z + x3.w*w.w;
    }

    const int vbase = blockIdx.x*16 + r0;
    xl[(vbase+0)*DD + lane] = acc0;
    xl[(vbase+1)*DD + lane] = acc1;
    xl[(vbase+2)*DD + lane] = acc2;
    xl[(vbase+3)*DD + lane] = acc3;

    const float ai = att_i[lane];
    const float aj = att_j[lane];
    float accs[4] = {acc0, acc1, acc2, acc3};
    #pragma unroll
    for (int r = 0; r < 4; ++r) {
        float pi = accs[r] * ai;
        float pj = accs[r] * aj;
        #pragma unroll
        for (int m = 32; m > 0; m >>= 1) {
            pi += __shfl_xor(pi, m);
            pj += __shfl_xor(pj, m);
        }
        if (lane == 0) {
            const int v = vbase + r;
            si[v] = pi + ei[v & (NN-1)];
            sj[v] = pj + ej[v & (NN-1)];
        }
    }
}

// ---------------------------------------------------------------------------
// K3: one wave per target. Softmax (lane=edge) then BATCHED float4 gather
// (9 loads in flight -> MLP), butterfly reduce, folded-BN epilogue.
// XCD-aware swizzle. Self-loop shfls outside divergence. (unchanged from R8)
// ---------------------------------------------------------------------------
__global__ void k3_agg(const float* __restrict__ xl, const float* __restrict__ si,
                       const float* __restrict__ sj, const int* __restrict__ topk,
                       const float* __restrict__ emb,
                       const float* __restrict__ epi,
                       const float* __restrict__ outW, const float* __restrict__ outb,
                       float* __restrict__ out) {
    const int t = threadIdx.x;
    const int lane = t & 63;
    const int wave = t >> 6;
    const int bid = blockIdx.x;              // 8192 blocks
    const int xcd = bid & 7;
    const int ixc = bid >> 3;                // 0..1023
    const int b   = xcd + 8 * (ixc >> 7);    // batch 0..63
    const int i   = ((ixc & 127) << 2) + wave;
    const int tgt = b * NN + i;

    // --- phase 1: lane k (0..32) = edge ---
    const bool isedge = (lane <= KK);
    int tk = i;
    bool valid = true;
    if (lane < KK) { tk = topk[i*KK + lane]; valid = (tk != i); }
    const int srcg = b * NN + tk;

    float a;
    if (isedge) {
        a = si[tgt] + sj[srcg];
        a = (a >= 0.f) ? a : NEG_SLOPE * a;   // leaky_relu
        if (!valid) a = NEG_INF_A;            // mask AFTER leaky (matches ref)
    } else {
        a = -3.0e38f;
    }

    float amax = a;
    #pragma unroll
    for (int m = 32; m > 0; m >>= 1) amax = fmaxf(amax, __shfl_xor(amax, m));

    float ex = (isedge && valid) ? __expf(a - amax) : 0.f;
    float denom = ex;
    #pragma unroll
    for (int m = 32; m > 0; m >>= 1) denom += __shfl_xor(denom, m);
    const float alpha = ex * __builtin_amdgcn_rcpf(denom);

    // --- phase 2: batched float4 gather, lane = (e4, c4) ---
    const int c4 = lane & 15;
    const int e4 = lane >> 4;
    const float4* xl4 = (const float4*)xl;

    float al[9];
    int   off[9];
    #pragma unroll
    for (int m = 0; m < 8; ++m) {
        const int kk = 4*m + e4;
        al[m]  = __shfl(alpha, kk);          // all lanes active
        off[m] = __shfl(srcg, kk)*16 + c4;
    }
    const float alpha32 = __shfl(alpha, KK); // full wave active
    const int   srcg32  = __shfl(srcg, KK);
    al[8]  = (e4 == 0) ? alpha32 : 0.f;
    off[8] = srcg32*16 + c4;

    float4 xv[9];
    #pragma unroll
    for (int m = 0; m < 9; ++m) xv[m] = xl4[off[m]];  // 9 loads in flight

    float4 acc = make_float4(0.f, 0.f, 0.f, 0.f);
    #pragma unroll
    for (int m = 0; m < 9; ++m) {
        acc.x += al[m]*xv[m].x; acc.y += al[m]*xv[m].y;
        acc.z += al[m]*xv[m].z; acc.w += al[m]*xv[m].w;
    }

    #pragma unroll
    for (int m = 16; m <= 32; m <<= 1) {
        acc.x += __shfl_xor(acc.x, m);
        acc.y += __shfl_xor(acc.y, m);
        acc.z += __shfl_xor(acc.z, m);
        acc.w += __shfl_xor(acc.w, m);
    }

    const float4* epi4 = (const float4*)epi;
    const float4 s1 = epi4[c4];
    const float4 B1 = epi4[16 + c4];
    const float4 so = epi4[32 + c4];
    const float4 Bo = epi4[48 + c4];
    const float4 em = ((const float4*)emb)[i*16 + c4];
    const float4 w4 = ((const float4*)outW)[c4];
    float4 h;
    h.x = fmaxf(acc.x*s1.x + B1.x, 0.f) * em.x;
    h.y = fmaxf(acc.y*s1.y + B1.y, 0.f) * em.y;
    h.z = fmaxf(acc.z*s1.z + B1.z, 0.f) * em.z;
    h.w = fmaxf(acc.w*s1.w + B1.w, 0.f) * em.w;
    h.x = fmaxf(h.x*so.x + Bo.x, 0.f);
    h.y = fmaxf(h.y*so.y + Bo.y, 0.f);
    h.z = fmaxf(h.z*so.z + Bo.z, 0.f);
    h.w = fmaxf(h.w*so.w + Bo.w, 0.f);
    float p = h.x*w4.x + h.y*w4.y + h.z*w4.z + h.w*w4.w;
    p += __shfl_xor(p, 1);
    p += __shfl_xor(p, 2);
    p += __shfl_xor(p, 4);
    p += __shfl_xor(p, 8);
    if (lane == 0) out[tgt] = p + outb[0];
}

// ---------------------------------------------------------------------------
extern "C" void kernel_launch(void* const* d_in, const int* in_sizes, int n_in,
                              void* d_out, int out_size, void* d_ws, size_t ws_size,
                              hipStream_t stream) {
    (void)in_sizes; (void)n_in; (void)out_size; (void)ws_size;
    const float* data   = (const float*)d_in[0];
    // d_in[1] = org_edge_index (int32) — unused by the reference forward
    const float* emb    = (const float*)d_in[2];
    const float* linW   = (const float*)d_in[3];
    const float* att_i  = (const float*)d_in[4];
    const float* att_j  = (const float*)d_in[5];
    const float* attemi = (const float*)d_in[6];
    const float* attemj = (const float*)d_in[7];
    const float* gbias  = (const float*)d_in[8];
    const float* g1     = (const float*)d_in[9];
    const float* b1     = (const float*)d_in[10];
    const float* m1     = (const float*)d_in[11];
    const float* v1     = (const float*)d_in[12];
    const float* go     = (const float*)d_in[13];
    const float* bo     = (const float*)d_in[14];
    const float* mo     = (const float*)d_in[15];
    const float* vo     = (const float*)d_in[16];
    const float* outW   = (const float*)d_in[17];
    const float* outb   = (const float*)d_in[18];
    float* out = (float*)d_out;

    // Workspace layout (bytes):
    //   ei @0 (2K)  ej @4K (2K)  epi @8K (1K)  topk @16K (64K)
    //   si @80K (128K)  sj @208K (128K)  xl @336K (8M)
    char* ws = (char*)d_ws;
    float* ei   = (float*)(ws + 0);
    float* ej   = (float*)(ws + 4096);
    float* epi  = (float*)(ws + 8192);
    int*   topk = (int*)  (ws + 16384);
    float* si   = (float*)(ws + 81920);
    float* sj   = (float*)(ws + 212992);
    float* xl   = (float*)(ws + 344064);

    kTop<<<NN, 256, 0, stream>>>(emb, attemi, attemj, gbias,
                                 g1, b1, m1, v1, go, bo, mo, vo,
                                 topk, ei, ej, epi);
    k2_lin<<<BN/16, 256, 0, stream>>>(data, linW, att_i, att_j, ei, ej,
                                      xl, si, sj);
    k3_agg<<<BN/4, 256, 0, stream>>>(xl, si, sj, topk, emb, epi,
                                     outW, outb, out);
}

// Round 10
// 138.737 us; speedup vs baseline: 1.0469x; 1.0469x over previous
//
#include <hip/hip_runtime.h>
#include <hip/hip_bf16.h>
#include <math.h>

// Problem constants (reference: B=64, N=512, K=32, D=64)
#define BB 64
#define NN 512
#define KK 32
#define DD 64
#define BN (BB*NN)          // 32768
#define EPSC 1e-5f
#define NEG_SLOPE 0.2f
#define NEG_INF_A (-1e9f)

typedef unsigned long long ull;

// Lessons carried: (R1) f32 inputs, not bf16. (R5) per-lane row loads from
// global are uncoalesced -> stage via LDS. (R6) lane*16+q LDS reads are
// 16-way bank-conflicted -> XOR swizzle slot = q ^ (row&15). (R7) never put
// __shfl under divergent control flow. (R9) don't fuse away tiling reuse:
// kA's 16x64 tiles beat a per-row mega-kernel that re-stages all of emb.

// ---------------------------------------------------------------------------
// KA: cos keys = order-preserving bits of (emb@emb^T)*rsqrt*rsqrt.
// Tile 16 rows x 64 cols; grid 32x8 = 256 blocks. B-tile XOR-swizzled in LDS.
// ---------------------------------------------------------------------------
__global__ void kA_cos(const float* __restrict__ emb, ull* __restrict__ keys) {
    __shared__ float4 As[256];       // 16 A-rows (4 KiB)
    __shared__ float4 Bs[1024];      // 64 B-rows (16 KiB), XOR-swizzled
    __shared__ float rsA[16];
    const int t = threadIdx.x;
    const int lane = t & 63;
    const int wave = t >> 6;
    const int bi = blockIdx.x >> 3;          // row tile (16 rows)
    const int c0 = (blockIdx.x & 7) * 64;    // col tile (64 rows)
    const float4* emb4 = (const float4*)emb;

    As[t] = emb4[bi*256 + t];                        // coalesced
    #pragma unroll
    for (int p = 0; p < 4; ++p) {                    // swizzled stage of B tile
        const int idx = t + 256*p;
        const int r = idx >> 4, q = idx & 15;
        Bs[(r<<4) | (q ^ (r & 15))] = emb4[c0*16 + idx];
    }
    __syncthreads();

    // wave 0: A-row inverse norms (lane = r*4+qq)
    if (wave == 0) {
        const int r = lane >> 2, qq = lane & 3;
        float ss = 0.f;
        #pragma unroll
        for (int m = 0; m < 4; ++m) {
            const float4 a = As[r*16 + qq*4 + m];
            ss += a.x*a.x + a.y*a.y + a.z*a.z + a.w*a.w;
        }
        ss += __shfl_xor(ss, 1);
        ss += __shfl_xor(ss, 2);
        if (qq == 0) rsA[r] = rsqrtf(ss);
    }

    // per-lane B-row fragment via swizzled ds_read_b128 + own norm
    float4 Wr[16];
    float ssW = 0.f;
    #pragma unroll
    for (int q = 0; q < 16; ++q) {
        Wr[q] = Bs[(lane<<4) | (q ^ (lane & 15))];
        ssW += Wr[q].x*Wr[q].x + Wr[q].y*Wr[q].y + Wr[q].z*Wr[q].z + Wr[q].w*Wr[q].w;
    }
    const float rsW = rsqrtf(ssW);
    __syncthreads();                         // rsA ready

    #pragma unroll
    for (int r = 0; r < 4; ++r) {
        const int jr = wave*4 + r;
        float acc = 0.f;
        #pragma unroll
        for (int q = 0; q < 16; ++q) {
            const float4 a = As[jr*16 + q];  // wave-uniform -> LDS broadcast
            const float4 w = Wr[q];
            acc += a.x*w.x + a.y*w.y + a.z*w.z + a.w*w.w;
        }
        const float c = acc * rsA[jr] * rsW;
        const int row = bi*16 + jr;
        const int col = c0 + lane;
        unsigned int u = __float_as_uint(c);
        u = (u & 0x80000000u) ? ~u : (u | 0x80000000u);  // order-preserving bits
        keys[row*NN + col] = ((ull)u << 16) | (ull)(NN - 1 - col);
    }
}

// ---------------------------------------------------------------------------
// KB: rank selection (block=row, thread=j) + ei/ej scalars + BN fold (blk 0).
// Keys unique -> rank = #{key > mine}; position rank = exact lax.top_k order.
// ---------------------------------------------------------------------------
__global__ void kB_rank(const ull* __restrict__ keys,
                        const float* __restrict__ emb,
                        const float* __restrict__ att_em_i,
                        const float* __restrict__ att_em_j,
                        const float* __restrict__ gnn_bias,
                        const float* __restrict__ g1, const float* __restrict__ b1,
                        const float* __restrict__ m1, const float* __restrict__ v1,
                        const float* __restrict__ go, const float* __restrict__ bo,
                        const float* __restrict__ mo, const float* __restrict__ vo,
                        int* __restrict__ topk,
                        float* __restrict__ ei, float* __restrict__ ej,
                        float* __restrict__ epi) {
    __shared__ ull ks[NN];
    const int i = blockIdx.x;
    const int t = threadIdx.x;               // 512 threads
    ks[t] = keys[i*NN + t];

    if (t < DD) {                            // whole wave 0: ei/ej for row i
        const float e = emb[i*DD + t];
        float e1 = e * att_em_i[t];
        float e2 = e * att_em_j[t];
        #pragma unroll
        for (int m = 32; m > 0; m >>= 1) {
            e1 += __shfl_xor(e1, m);
            e2 += __shfl_xor(e2, m);
        }
        if (t == 0) { ei[i] = e1; ej[i] = e2; }
    }
    if (i == 0 && t >= 64 && t < 64 + DD) {  // block 0: fold BN constants
        const int d = t - 64;
        float s1 = g1[d] / sqrtf(v1[d] + EPSC);
        float B1 = (gnn_bias[d] - m1[d]) * s1 + b1[d];
        float so = go[d] / sqrtf(vo[d] + EPSC);
        float Bo = bo[d] - mo[d] * so;
        epi[d] = s1; epi[DD + d] = B1; epi[2*DD + d] = so; epi[3*DD + d] = Bo;
    }
    __syncthreads();
    const ull mykey = ks[t];
    int rank = 0;
    #pragma unroll 16
    for (int kk = 0; kk < NN; ++kk) rank += (ks[kk] > mykey) ? 1 : 0;
    if (rank < KK) topk[i*KK + rank] = t;
}

// ---------------------------------------------------------------------------
// K2: xl = x @ lin_W^T + si/sj. W staged to LDS with XOR swizzle. R10: 32
// rows per block (1024 blocks) -- halves W re-stage traffic + sync overhead.
// ---------------------------------------------------------------------------
__global__ void k2_lin(const float* __restrict__ data,
                       const float* __restrict__ linW,
                       const float* __restrict__ att_i, const float* __restrict__ att_j,
                       const float* __restrict__ ei, const float* __restrict__ ej,
                       float* __restrict__ xl, float* __restrict__ si,
                       float* __restrict__ sj) {
    __shared__ float4 Ws[1024];         // full W, 16 KiB, XOR-swizzled
    __shared__ float4 xs[512];          // 32 rows x 16 float4 = 8 KiB
    const int t = threadIdx.x;
    const int lane = t & 63;
    const int wave = t >> 6;
    const float4* W4 = (const float4*)linW;

    #pragma unroll
    for (int p = 0; p < 4; ++p) {       // swizzled full-W stage (coalesced)
        const int idx = t + 256*p;
        const int r = idx >> 4, q = idx & 15;
        Ws[(r<<4) | (q ^ (r & 15))] = W4[idx];
    }
    xs[t]       = ((const float4*)data)[blockIdx.x*512 + t];
    xs[t + 256] = ((const float4*)data)[blockIdx.x*512 + t + 256];
    __syncthreads();

    float4 Wr[16];                      // W[lane][0..63], swizzled read
    #pragma unroll
    for (int q = 0; q < 16; ++q) Wr[q] = Ws[(lane<<4) | (q ^ (lane & 15))];

    const int r0 = wave * 8;            // 8 rows per wave
    float acc[8] = {0.f, 0.f, 0.f, 0.f, 0.f, 0.f, 0.f, 0.f};
    #pragma unroll
    for (int q = 0; q < 16; ++q) {
        const float4 w = Wr[q];
        #pragma unroll
        for (int r = 0; r < 8; ++r) {
            const float4 x = xs[(r0+r)*16 + q];   // wave-uniform broadcasts
            acc[r] += x.x*w.x + x.y*w.y + x.z*w.z + x.w*w.w;
        }
    }

    const int vbase = blockIdx.x*32 + r0;
    #pragma unroll
    for (int r = 0; r < 8; ++r) xl[(vbase+r)*DD + lane] = acc[r];

    const float ai = att_i[lane];
    const float aj = att_j[lane];
    #pragma unroll
    for (int r = 0; r < 8; ++r) {
        float pi = acc[r] * ai;
        float pj = acc[r] * aj;
        #pragma unroll
        for (int m = 32; m > 0; m >>= 1) {
            pi += __shfl_xor(pi, m);
            pj += __shfl_xor(pj, m);
        }
        if (lane == 0) {
            const int v = vbase + r;
            si[v] = pi + ei[v & (NN-1)];
            sj[v] = pj + ej[v & (NN-1)];
        }
    }
}

// ---------------------------------------------------------------------------
// K3: one wave per target. Softmax (lane=edge) then BATCHED float4 gather
// (9 loads in flight -> MLP), butterfly reduce, folded-BN epilogue.
// XCD-aware swizzle. Self-loop shfls outside divergence. (unchanged from R8)
// ---------------------------------------------------------------------------
__global__ void k3_agg(const float* __restrict__ xl, const float* __restrict__ si,
                       const float* __restrict__ sj, const int* __restrict__ topk,
                       const float* __restrict__ emb,
                       const float* __restrict__ epi,
                       const float* __restrict__ outW, const float* __restrict__ outb,
                       float* __restrict__ out) {
    const int t = threadIdx.x;
    const int lane = t & 63;
    const int wave = t >> 6;
    const int bid = blockIdx.x;              // 8192 blocks
    const int xcd = bid & 7;
    const int ixc = bid >> 3;                // 0..1023
    const int b   = xcd + 8 * (ixc >> 7);    // batch 0..63
    const int i   = ((ixc & 127) << 2) + wave;
    const int tgt = b * NN + i;

    // --- phase 1: lane k (0..32) = edge ---
    const bool isedge = (lane <= KK);
    int tk = i;
    bool valid = true;
    if (lane < KK) { tk = topk[i*KK + lane]; valid = (tk != i); }
    const int srcg = b * NN + tk;

    float a;
    if (isedge) {
        a = si[tgt] + sj[srcg];
        a = (a >= 0.f) ? a : NEG_SLOPE * a;   // leaky_relu
        if (!valid) a = NEG_INF_A;            // mask AFTER leaky (matches ref)
    } else {
        a = -3.0e38f;
    }

    float amax = a;
    #pragma unroll
    for (int m = 32; m > 0; m >>= 1) amax = fmaxf(amax, __shfl_xor(amax, m));

    float ex = (isedge && valid) ? __expf(a - amax) : 0.f;
    float denom = ex;
    #pragma unroll
    for (int m = 32; m > 0; m >>= 1) denom += __shfl_xor(denom, m);
    const float alpha = ex * __builtin_amdgcn_rcpf(denom);

    // --- phase 2: batched float4 gather, lane = (e4, c4) ---
    const int c4 = lane & 15;
    const int e4 = lane >> 4;
    const float4* xl4 = (const float4*)xl;

    float al[9];
    int   off[9];
    #pragma unroll
    for (int m = 0; m < 8; ++m) {
        const int kk = 4*m + e4;
        al[m]  = __shfl(alpha, kk);          // all lanes active
        off[m] = __shfl(srcg, kk)*16 + c4;
    }
    const float alpha32 = __shfl(alpha, KK); // full wave active
    const int   srcg32  = __shfl(srcg, KK);
    al[8]  = (e4 == 0) ? alpha32 : 0.f;
    off[8] = srcg32*16 + c4;

    float4 xv[9];
    #pragma unroll
    for (int m = 0; m < 9; ++m) xv[m] = xl4[off[m]];  // 9 loads in flight

    float4 acc = make_float4(0.f, 0.f, 0.f, 0.f);
    #pragma unroll
    for (int m = 0; m < 9; ++m) {
        acc.x += al[m]*xv[m].x; acc.y += al[m]*xv[m].y;
        acc.z += al[m]*xv[m].z; acc.w += al[m]*xv[m].w;
    }

    #pragma unroll
    for (int m = 16; m <= 32; m <<= 1) {
        acc.x += __shfl_xor(acc.x, m);
        acc.y += __shfl_xor(acc.y, m);
        acc.z += __shfl_xor(acc.z, m);
        acc.w += __shfl_xor(acc.w, m);
    }

    const float4* epi4 = (const float4*)epi;
    const float4 s1 = epi4[c4];
    const float4 B1 = epi4[16 + c4];
    const float4 so = epi4[32 + c4];
    const float4 Bo = epi4[48 + c4];
    const float4 em = ((const float4*)emb)[i*16 + c4];
    const float4 w4 = ((const float4*)outW)[c4];
    float4 h;
    h.x = fmaxf(acc.x*s1.x + B1.x, 0.f) * em.x;
    h.y = fmaxf(acc.y*s1.y + B1.y, 0.f) * em.y;
    h.z = fmaxf(acc.z*s1.z + B1.z, 0.f) * em.z;
    h.w = fmaxf(acc.w*s1.w + B1.w, 0.f) * em.w;
    h.x = fmaxf(h.x*so.x + Bo.x, 0.f);
    h.y = fmaxf(h.y*so.y + Bo.y, 0.f);
    h.z = fmaxf(h.z*so.z + Bo.z, 0.f);
    h.w = fmaxf(h.w*so.w + Bo.w, 0.f);
    float p = h.x*w4.x + h.y*w4.y + h.z*w4.z + h.w*w4.w;
    p += __shfl_xor(p, 1);
    p += __shfl_xor(p, 2);
    p += __shfl_xor(p, 4);
    p += __shfl_xor(p, 8);
    if (lane == 0) out[tgt] = p + outb[0];
}

// ---------------------------------------------------------------------------
extern "C" void kernel_launch(void* const* d_in, const int* in_sizes, int n_in,
                              void* d_out, int out_size, void* d_ws, size_t ws_size,
                              hipStream_t stream) {
    (void)in_sizes; (void)n_in; (void)out_size; (void)ws_size;
    const float* data   = (const float*)d_in[0];
    // d_in[1] = org_edge_index (int32) — unused by the reference forward
    const float* emb    = (const float*)d_in[2];
    const float* linW   = (const float*)d_in[3];
    const float* att_i  = (const float*)d_in[4];
    const float* att_j  = (const float*)d_in[5];
    const float* attemi = (const float*)d_in[6];
    const float* attemj = (const float*)d_in[7];
    const float* gbias  = (const float*)d_in[8];
    const float* g1     = (const float*)d_in[9];
    const float* b1     = (const float*)d_in[10];
    const float* m1     = (const float*)d_in[11];
    const float* v1     = (const float*)d_in[12];
    const float* go     = (const float*)d_in[13];
    const float* bo     = (const float*)d_in[14];
    const float* mo     = (const float*)d_in[15];
    const float* vo     = (const float*)d_in[16];
    const float* outW   = (const float*)d_in[17];
    const float* outb   = (const float*)d_in[18];
    float* out = (float*)d_out;

    // Workspace layout (bytes):
    //   ei @0 (2K)  ej @4K (2K)  epi @8K (1K)  topk @16K (64K)
    //   si @80K (128K)  sj @208K (128K)
    //   xl @336K (8M) [k2->k3]  /  keys @336K (2M) [kA->kB, dead before k2]
    char* ws = (char*)d_ws;
    float* ei   = (float*)(ws + 0);
    float* ej   = (float*)(ws + 4096);
    float* epi  = (float*)(ws + 8192);
    int*   topk = (int*)  (ws + 16384);
    float* si   = (float*)(ws + 81920);
    float* sj   = (float*)(ws + 212992);
    float* xl   = (float*)(ws + 344064);
    ull*   keys = (ull*)  (ws + 344064);

    kA_cos<<<256, 256, 0, stream>>>(emb, keys);
    kB_rank<<<NN, NN, 0, stream>>>(keys, emb, attemi, attemj, gbias,
                                   g1, b1, m1, v1, go, bo, mo, vo,
                                   topk, ei, ej, epi);
    k2_lin<<<BN/32, 256, 0, stream>>>(data, linW, att_i, att_j, ei, ej,
                                      xl, si, sj);
    k3_agg<<<BN/4, 256, 0, stream>>>(xl, si, sj, topk, emb, epi,
                                     outW, outb, out);
}

// Round 11
// 136.018 us; speedup vs baseline: 1.0678x; 1.0200x over previous
//
#include <hip/hip_runtime.h>
#include <hip/hip_bf16.h>
#include <math.h>

// Problem constants (reference: B=64, N=512, K=32, D=64)
#define BB 64
#define NN 512
#define KK 32
#define DD 64
#define BN (BB*NN)          // 32768
#define EPSC 1e-5f
#define NEG_SLOPE 0.2f
#define NEG_INF_A (-1e9f)

typedef unsigned long long ull;

// Lessons carried: (R1) f32 inputs, not bf16. (R5) per-lane row loads from
// global are uncoalesced -> stage via LDS. (R6) lane*16+q LDS reads are
// 16-way bank-conflicted -> XOR swizzle slot = q ^ (row&15). (R7) never put
// __shfl under divergent control flow. (R9) don't fuse away tiling reuse.
// (R10+) producer/consumer XCD alignment: k2 writes xl for batch b on XCD
// b%8, where k3's readers of batch b also run -> gathers hit local L2.

// ---------------------------------------------------------------------------
// KA: cos keys = order-preserving bits of (emb@emb^T)*rsqrt*rsqrt.
// Tile 16 rows x 64 cols; grid 32x8 = 256 blocks. B-tile XOR-swizzled in LDS.
// ---------------------------------------------------------------------------
__global__ void kA_cos(const float* __restrict__ emb, ull* __restrict__ keys) {
    __shared__ float4 As[256];       // 16 A-rows (4 KiB)
    __shared__ float4 Bs[1024];      // 64 B-rows (16 KiB), XOR-swizzled
    __shared__ float rsA[16];
    const int t = threadIdx.x;
    const int lane = t & 63;
    const int wave = t >> 6;
    const int bi = blockIdx.x >> 3;          // row tile (16 rows)
    const int c0 = (blockIdx.x & 7) * 64;    // col tile (64 rows)
    const float4* emb4 = (const float4*)emb;

    As[t] = emb4[bi*256 + t];                        // coalesced
    #pragma unroll
    for (int p = 0; p < 4; ++p) {                    // swizzled stage of B tile
        const int idx = t + 256*p;
        const int r = idx >> 4, q = idx & 15;
        Bs[(r<<4) | (q ^ (r & 15))] = emb4[c0*16 + idx];
    }
    __syncthreads();

    // wave 0: A-row inverse norms (lane = r*4+qq)
    if (wave == 0) {
        const int r = lane >> 2, qq = lane & 3;
        float ss = 0.f;
        #pragma unroll
        for (int m = 0; m < 4; ++m) {
            const float4 a = As[r*16 + qq*4 + m];
            ss += a.x*a.x + a.y*a.y + a.z*a.z + a.w*a.w;
        }
        ss += __shfl_xor(ss, 1);
        ss += __shfl_xor(ss, 2);
        if (qq == 0) rsA[r] = rsqrtf(ss);
    }

    // per-lane B-row fragment via swizzled ds_read_b128 + own norm
    float4 Wr[16];
    float ssW = 0.f;
    #pragma unroll
    for (int q = 0; q < 16; ++q) {
        Wr[q] = Bs[(lane<<4) | (q ^ (lane & 15))];
        ssW += Wr[q].x*Wr[q].x + Wr[q].y*Wr[q].y + Wr[q].z*Wr[q].z + Wr[q].w*Wr[q].w;
    }
    const float rsW = rsqrtf(ssW);
    __syncthreads();                         // rsA ready

    #pragma unroll
    for (int r = 0; r < 4; ++r) {
        const int jr = wave*4 + r;
        float acc = 0.f;
        #pragma unroll
        for (int q = 0; q < 16; ++q) {
            const float4 a = As[jr*16 + q];  // wave-uniform -> LDS broadcast
            const float4 w = Wr[q];
            acc += a.x*w.x + a.y*w.y + a.z*w.z + a.w*w.w;
        }
        const float c = acc * rsA[jr] * rsW;
        const int row = bi*16 + jr;
        const int col = c0 + lane;
        unsigned int u = __float_as_uint(c);
        u = (u & 0x80000000u) ? ~u : (u | 0x80000000u);  // order-preserving bits
        keys[row*NN + col] = ((ull)u << 16) | (ull)(NN - 1 - col);
    }
}

// ---------------------------------------------------------------------------
// KB: rank selection (block=row, thread=j) + ei/ej scalars + BN fold (blk 0).
// Keys unique -> rank = #{key > mine}; position rank = exact lax.top_k order.
// ---------------------------------------------------------------------------
__global__ void kB_rank(const ull* __restrict__ keys,
                        const float* __restrict__ emb,
                        const float* __restrict__ att_em_i,
                        const float* __restrict__ att_em_j,
                        const float* __restrict__ gnn_bias,
                        const float* __restrict__ g1, const float* __restrict__ b1,
                        const float* __restrict__ m1, const float* __restrict__ v1,
                        const float* __restrict__ go, const float* __restrict__ bo,
                        const float* __restrict__ mo, const float* __restrict__ vo,
                        int* __restrict__ topk,
                        float* __restrict__ ei, float* __restrict__ ej,
                        float* __restrict__ epi) {
    __shared__ ull ks[NN];
    const int i = blockIdx.x;
    const int t = threadIdx.x;               // 512 threads
    ks[t] = keys[i*NN + t];

    if (t < DD) {                            // whole wave 0: ei/ej for row i
        const float e = emb[i*DD + t];
        float e1 = e * att_em_i[t];
        float e2 = e * att_em_j[t];
        #pragma unroll
        for (int m = 32; m > 0; m >>= 1) {
            e1 += __shfl_xor(e1, m);
            e2 += __shfl_xor(e2, m);
        }
        if (t == 0) { ei[i] = e1; ej[i] = e2; }
    }
    if (i == 0 && t >= 64 && t < 64 + DD) {  // block 0: fold BN constants
        const int d = t - 64;
        float s1 = g1[d] / sqrtf(v1[d] + EPSC);
        float B1 = (gnn_bias[d] - m1[d]) * s1 + b1[d];
        float so = go[d] / sqrtf(vo[d] + EPSC);
        float Bo = bo[d] - mo[d] * so;
        epi[d] = s1; epi[DD + d] = B1; epi[2*DD + d] = so; epi[3*DD + d] = Bo;
    }
    __syncthreads();
    const ull mykey = ks[t];
    int rank = 0;
    #pragma unroll 16
    for (int kk = 0; kk < NN; ++kk) rank += (ks[kk] > mykey) ? 1 : 0;
    if (rank < KK) topk[i*KK + rank] = t;
}

// ---------------------------------------------------------------------------
// K2: xl = x @ lin_W^T + si/sj. 32 rows/block, 1024 blocks. XCD-ALIGNED row
// mapping: block bid runs on XCD bid%8 (round-robin heuristic); rows of
// batch b are assigned to blocks with bid%8 == b%8, matching k3's consumer
// swizzle -> xl stays in the local XCD L2.
// ---------------------------------------------------------------------------
__global__ void k2_lin(const float* __restrict__ data,
                       const float* __restrict__ linW,
                       const float* __restrict__ att_i, const float* __restrict__ att_j,
                       const float* __restrict__ ei, const float* __restrict__ ej,
                       float* __restrict__ xl, float* __restrict__ si,
                       float* __restrict__ sj) {
    __shared__ float4 Ws[1024];         // full W, 16 KiB, XOR-swizzled
    __shared__ float4 xs[512];          // 32 rows x 16 float4 = 8 KiB
    const int t = threadIdx.x;
    const int lane = t & 63;
    const int wave = t >> 6;
    const float4* W4 = (const float4*)linW;

    // XCD-aligned mapping: batch = xcd + 8*(j>>4); 16 sub-blocks per batch.
    const int bid = blockIdx.x;          // 0..1023
    const int xcd = bid & 7;
    const int j   = bid >> 3;            // 0..127
    const int batch = xcd + 8 * (j >> 4);
    const int sub   = j & 15;
    const int row0  = batch * NN + sub * 32;   // 32 rows, all in batch `batch`

    #pragma unroll
    for (int p = 0; p < 4; ++p) {       // swizzled full-W stage (coalesced)
        const int idx = t + 256*p;
        const int r = idx >> 4, q = idx & 15;
        Ws[(r<<4) | (q ^ (r & 15))] = W4[idx];
    }
    xs[t]       = ((const float4*)data)[row0*16 + t];
    xs[t + 256] = ((const float4*)data)[row0*16 + t + 256];
    __syncthreads();

    float4 Wr[16];                      // W[lane][0..63], swizzled read
    #pragma unroll
    for (int q = 0; q < 16; ++q) Wr[q] = Ws[(lane<<4) | (q ^ (lane & 15))];

    const int r0 = wave * 8;            // 8 rows per wave
    float acc[8] = {0.f, 0.f, 0.f, 0.f, 0.f, 0.f, 0.f, 0.f};
    #pragma unroll
    for (int q = 0; q < 16; ++q) {
        const float4 w = Wr[q];
        #pragma unroll
        for (int r = 0; r < 8; ++r) {
            const float4 x = xs[(r0+r)*16 + q];   // wave-uniform broadcasts
            acc[r] += x.x*w.x + x.y*w.y + x.z*w.z + x.w*w.w;
        }
    }

    const int vbase = row0 + r0;
    #pragma unroll
    for (int r = 0; r < 8; ++r) xl[(vbase+r)*DD + lane] = acc[r];

    const float ai = att_i[lane];
    const float aj = att_j[lane];
    #pragma unroll
    for (int r = 0; r < 8; ++r) {
        float pi = acc[r] * ai;
        float pj = acc[r] * aj;
        #pragma unroll
        for (int m = 32; m > 0; m >>= 1) {
            pi += __shfl_xor(pi, m);
            pj += __shfl_xor(pj, m);
        }
        if (lane == 0) {
            const int v = vbase + r;
            si[v] = pi + ei[v & (NN-1)];
            sj[v] = pj + ej[v & (NN-1)];
        }
    }
}

// ---------------------------------------------------------------------------
// K3: one wave per target. Softmax (lane=edge) then BATCHED float4 gather
// (9 loads in flight -> MLP), butterfly reduce, folded-BN epilogue.
// XCD swizzle: batch b on XCD b%8 (matches k2's producer placement).
// ---------------------------------------------------------------------------
__global__ void k3_agg(const float* __restrict__ xl, const float* __restrict__ si,
                       const float* __restrict__ sj, const int* __restrict__ topk,
                       const float* __restrict__ emb,
                       const float* __restrict__ epi,
                       const float* __restrict__ outW, const float* __restrict__ outb,
                       float* __restrict__ out) {
    const int t = threadIdx.x;
    const int lane = t & 63;
    const int wave = t >> 6;
    const int bid = blockIdx.x;              // 8192 blocks
    const int xcd = bid & 7;
    const int ixc = bid >> 3;                // 0..1023
    const int b   = xcd + 8 * (ixc >> 7);    // batch 0..63, b%8 == xcd
    const int i   = ((ixc & 127) << 2) + wave;
    const int tgt = b * NN + i;

    // --- phase 1: lane k (0..32) = edge ---
    const bool isedge = (lane <= KK);
    int tk = i;
    bool valid = true;
    if (lane < KK) { tk = topk[i*KK + lane]; valid = (tk != i); }
    const int srcg = b * NN + tk;

    float a;
    if (isedge) {
        a = si[tgt] + sj[srcg];
        a = (a >= 0.f) ? a : NEG_SLOPE * a;   // leaky_relu
        if (!valid) a = NEG_INF_A;            // mask AFTER leaky (matches ref)
    } else {
        a = -3.0e38f;
    }

    float amax = a;
    #pragma unroll
    for (int m = 32; m > 0; m >>= 1) amax = fmaxf(amax, __shfl_xor(amax, m));

    float ex = (isedge && valid) ? __expf(a - amax) : 0.f;
    float denom = ex;
    #pragma unroll
    for (int m = 32; m > 0; m >>= 1) denom += __shfl_xor(denom, m);
    const float alpha = ex * __builtin_amdgcn_rcpf(denom);

    // --- phase 2: batched float4 gather, lane = (e4, c4) ---
    const int c4 = lane & 15;
    const int e4 = lane >> 4;
    const float4* xl4 = (const float4*)xl;

    float al[9];
    int   off[9];
    #pragma unroll
    for (int m = 0; m < 8; ++m) {
        const int kk = 4*m + e4;
        al[m]  = __shfl(alpha, kk);          // all lanes active
        off[m] = __shfl(srcg, kk)*16 + c4;
    }
    const float alpha32 = __shfl(alpha, KK); // full wave active
    const int   srcg32  = __shfl(srcg, KK);
    al[8]  = (e4 == 0) ? alpha32 : 0.f;
    off[8] = srcg32*16 + c4;

    float4 xv[9];
    #pragma unroll
    for (int m = 0; m < 9; ++m) xv[m] = xl4[off[m]];  // 9 loads in flight

    float4 acc = make_float4(0.f, 0.f, 0.f, 0.f);
    #pragma unroll
    for (int m = 0; m < 9; ++m) {
        acc.x += al[m]*xv[m].x; acc.y += al[m]*xv[m].y;
        acc.z += al[m]*xv[m].z; acc.w += al[m]*xv[m].w;
    }

    #pragma unroll
    for (int m = 16; m <= 32; m <<= 1) {
        acc.x += __shfl_xor(acc.x, m);
        acc.y += __shfl_xor(acc.y, m);
        acc.z += __shfl_xor(acc.z, m);
        acc.w += __shfl_xor(acc.w, m);
    }

    const float4* epi4 = (const float4*)epi;
    const float4 s1 = epi4[c4];
    const float4 B1 = epi4[16 + c4];
    const float4 so = epi4[32 + c4];
    const float4 Bo = epi4[48 + c4];
    const float4 em = ((const float4*)emb)[i*16 + c4];
    const float4 w4 = ((const float4*)outW)[c4];
    float4 h;
    h.x = fmaxf(acc.x*s1.x + B1.x, 0.f) * em.x;
    h.y = fmaxf(acc.y*s1.y + B1.y, 0.f) * em.y;
    h.z = fmaxf(acc.z*s1.z + B1.z, 0.f) * em.z;
    h.w = fmaxf(acc.w*s1.w + B1.w, 0.f) * em.w;
    h.x = fmaxf(h.x*so.x + Bo.x, 0.f);
    h.y = fmaxf(h.y*so.y + Bo.y, 0.f);
    h.z = fmaxf(h.z*so.z + Bo.z, 0.f);
    h.w = fmaxf(h.w*so.w + Bo.w, 0.f);
    float p = h.x*w4.x + h.y*w4.y + h.z*w4.z + h.w*w4.w;
    p += __shfl_xor(p, 1);
    p += __shfl_xor(p, 2);
    p += __shfl_xor(p, 4);
    p += __shfl_xor(p, 8);
    if (lane == 0) out[tgt] = p + outb[0];
}

// ---------------------------------------------------------------------------
extern "C" void kernel_launch(void* const* d_in, const int* in_sizes, int n_in,
                              void* d_out, int out_size, void* d_ws, size_t ws_size,
                              hipStream_t stream) {
    (void)in_sizes; (void)n_in; (void)out_size; (void)ws_size;
    const float* data   = (const float*)d_in[0];
    // d_in[1] = org_edge_index (int32) — unused by the reference forward
    const float* emb    = (const float*)d_in[2];
    const float* linW   = (const float*)d_in[3];
    const float* att_i  = (const float*)d_in[4];
    const float* att_j  = (const float*)d_in[5];
    const float* attemi = (const float*)d_in[6];
    const float* attemj = (const float*)d_in[7];
    const float* gbias  = (const float*)d_in[8];
    const float* g1     = (const float*)d_in[9];
    const float* b1     = (const float*)d_in[10];
    const float* m1     = (const float*)d_in[11];
    const float* v1     = (const float*)d_in[12];
    const float* go     = (const float*)d_in[13];
    const float* bo     = (const float*)d_in[14];
    const float* mo     = (const float*)d_in[15];
    const float* vo     = (const float*)d_in[16];
    const float* outW   = (const float*)d_in[17];
    const float* outb   = (const float*)d_in[18];
    float* out = (float*)d_out;

    // Workspace layout (bytes):
    //   ei @0 (2K)  ej @4K (2K)  epi @8K (1K)  topk @16K (64K)
    //   si @80K (128K)  sj @208K (128K)
    //   xl @336K (8M) [k2->k3]  /  keys @336K (2M) [kA->kB, dead before k2]
    char* ws = (char*)d_ws;
    float* ei   = (float*)(ws + 0);
    float* ej   = (float*)(ws + 4096);
    float* epi  = (float*)(ws + 8192);
    int*   topk = (int*)  (ws + 16384);
    float* si   = (float*)(ws + 81920);
    float* sj   = (float*)(ws + 212992);
    float* xl   = (float*)(ws + 344064);
    ull*   keys = (ull*)  (ws + 344064);

    kA_cos<<<256, 256, 0, stream>>>(emb, keys);
    kB_rank<<<NN, NN, 0, stream>>>(keys, emb, attemi, attemj, gbias,
                                   g1, b1, m1, v1, go, bo, mo, vo,
                                   topk, ei, ej, epi);
    k2_lin<<<BN/32, 256, 0, stream>>>(data, linW, att_i, att_j, ei, ej,
                                      xl, si, sj);
    k3_agg<<<BN/4, 256, 0, stream>>>(xl, si, sj, topk, emb, epi,
                                     outW, outb, out);
}